// Round 5
// baseline (668.163 us; speedup 1.0000x reference)
//
#include <hip/hip_runtime.h>
#include <math.h>

#define N_NODES 50000
#define E_EDGES 250000
#define HID 64
#define HD 256          // NHEADS * HID
#define L_LAYERS 2
#define IN_DIM_ 256
#define ATT_SCALE 0.125f
#define LOG2E 1.44269504f
#define EPS_BN 1e-5f
#define NCHUNK 49       // ceil(50000/1024)

typedef __attribute__((ext_vector_type(8))) short bf16x8;
typedef __attribute__((ext_vector_type(4))) float f32x4;

static __device__ __forceinline__ unsigned short f2bf(float f) {
    unsigned u = __float_as_uint(f);
    unsigned r = (u + 0x7fff + ((u >> 16) & 1)) >> 16;
    return (unsigned short)r;
}
static __device__ __forceinline__ float bf2f(unsigned u) {
    return __uint_as_float(u << 16);
}

// sum across each 16-lane row via DPP butterfly (4 VALU adds, no LDS)
static __device__ __forceinline__ float rowsum16(float x) {
    int t;
    t = __builtin_amdgcn_update_dpp(0, __float_as_int(x), 0xB1, 0xf, 0xf, true);  // quad_perm(1,0,3,2)
    x += __int_as_float(t);
    t = __builtin_amdgcn_update_dpp(0, __float_as_int(x), 0x4E, 0xf, 0xf, true);  // quad_perm(2,3,0,1)
    x += __int_as_float(t);
    t = __builtin_amdgcn_update_dpp(0, __float_as_int(x), 0x141, 0xf, 0xf, true); // row_half_mirror
    x += __int_as_float(t);
    t = __builtin_amdgcn_update_dpp(0, __float_as_int(x), 0x140, 0xf, 0xf, true); // row_mirror
    x += __int_as_float(t);
    return x;
}

// ----------------------------- CSR build ------------------------------------

__global__ void hist_kernel(const int* __restrict__ d0, const int* __restrict__ d1,
                            const int* __restrict__ d2, int* __restrict__ count) {
    int i = blockIdx.x * blockDim.x + threadIdx.x;
    if (i >= 3 * E_EDGES) return;
    int r = i / E_EDGES;
    int e = i - r * E_EDGES;
    const int* dst = (r == 0) ? d0 : ((r == 1) ? d1 : d2);
    atomicAdd(&count[r * N_NODES + dst[e]], 1);
}

__global__ __launch_bounds__(256) void scan_partial(const int* __restrict__ count,
                                                    int* __restrict__ bsum) {
    int b = blockIdx.x;                 // 0..146
    int r = b / NCHUNK, ch = b - r * NCHUNK;
    int tid = threadIdx.x;
    int i0 = ch * 1024 + tid * 4;
    int s = 0;
    if (i0 + 3 < N_NODES) {
        int4 v = *(const int4*)(count + r * N_NODES + i0);
        s = v.x + v.y + v.z + v.w;
    } else {
        for (int j = 0; j < 4; ++j)
            if (i0 + j < N_NODES) s += count[r * N_NODES + i0 + j];
    }
    for (int o = 1; o < 64; o <<= 1) s += __shfl_xor(s, o, 64);
    __shared__ int wsum[4];
    if ((tid & 63) == 0) wsum[tid >> 6] = s;
    __syncthreads();
    if (tid == 0) bsum[b] = wsum[0] + wsum[1] + wsum[2] + wsum[3];
}

__global__ __launch_bounds__(256) void scan_mid(const int* __restrict__ bsum,
                                                int* __restrict__ bpre) {
    __shared__ int A[256], B[256];
    int tid = threadIdx.x;
    int v = (tid < 3 * NCHUNK) ? bsum[tid] : 0;
    int segStart = (tid / NCHUNK) * NCHUNK;
    A[tid] = v;
    __syncthreads();
    int* s = A; int* d = B;
    for (int o = 1; o < 256; o <<= 1) {
        int x = s[tid];
        if (tid - o >= segStart) x += s[tid - o];
        d[tid] = x;
        __syncthreads();
        int* t = s; s = d; d = t;
    }
    if (tid < 3 * NCHUNK) bpre[tid] = s[tid] - v;
}

__global__ __launch_bounds__(256) void scan_final(const int* __restrict__ count,
                                                  const int* __restrict__ bpre,
                                                  int* __restrict__ row_off,
                                                  int* __restrict__ cursor) {
    int b = blockIdx.x;
    int r = b / NCHUNK, ch = b - r * NCHUNK;
    int tid = threadIdx.x;
    int i0 = ch * 1024 + tid * 4;
    int v[4] = {0, 0, 0, 0};
    if (i0 + 3 < N_NODES) {
        int4 t = *(const int4*)(count + r * N_NODES + i0);
        v[0] = t.x; v[1] = t.y; v[2] = t.z; v[3] = t.w;
    } else {
        for (int j = 0; j < 4; ++j)
            if (i0 + j < N_NODES) v[j] = count[r * N_NODES + i0 + j];
    }
    int tsum = v[0] + v[1] + v[2] + v[3];
    __shared__ int A[256], B[256];
    A[tid] = tsum;
    __syncthreads();
    int* s = A; int* d = B;
    for (int o = 1; o < 256; o <<= 1) {
        int x = s[tid];
        if (tid >= o) x += s[tid - o];
        d[tid] = x;
        __syncthreads();
        int* t = s; s = d; d = t;
    }
    int run = bpre[b] + s[tid] - tsum;
    int* ro = row_off + r * (N_NODES + 1);
    int* cu = cursor + r * N_NODES;
    for (int j = 0; j < 4; ++j) {
        int idx = i0 + j;
        if (idx < N_NODES) { ro[idx] = run; cu[idx] = run; run += v[j]; }
    }
    if (ch == NCHUNK - 1 && tid == 255) ro[N_NODES] = E_EDGES;
}

__global__ void scatter_kernel(const int* __restrict__ s0, const int* __restrict__ d0,
                               const int* __restrict__ s1, const int* __restrict__ d1,
                               const int* __restrict__ s2, const int* __restrict__ d2,
                               int* __restrict__ cursor, int* __restrict__ csr_src) {
    int i = blockIdx.x * blockDim.x + threadIdx.x;
    if (i >= 3 * E_EDGES) return;
    int r = i / E_EDGES;
    int e = i - r * E_EDGES;
    const int* src = (r == 0) ? s0 : ((r == 1) ? s1 : s2);
    const int* dst = (r == 0) ? d0 : ((r == 1) ? d1 : d2);
    int d = dst[e];
    int pos = atomicAdd(&cursor[r * N_NODES + d], 1);
    csr_src[r * E_EDGES + pos] = src[e];
}

// --------------------------- weight packing (merged) -------------------------
// seg0: WtRel [6][512][64]  seg1: WtFc [2][64][64]  seg2: WtDim [256][64]

#define PACK_REL (6 * 512 * 64)
#define PACK_FC  (2 * 64 * 64)
#define PACK_DIM (256 * 64)

__global__ void pack_all(const float* __restrict__ Wsrc, const float* __restrict__ Wdst,
                         const float* __restrict__ Wfc, const float* __restrict__ Wdim,
                         unsigned short* __restrict__ WtRel, unsigned short* __restrict__ WtFc,
                         unsigned short* __restrict__ WtDim) {
    int i = blockIdx.x * 256 + threadIdx.x;
    if (i < PACK_REL) {
        int k = i & 63;
        int n = (i >> 6) & 511;
        int lr = i >> 15;
        const float* srcm = (n < 256) ? Wsrc : Wdst;
        WtRel[i] = f2bf(srcm[((size_t)lr * 64 + k) * 256 + (n & 255)]);
    } else if (i < PACK_REL + PACK_FC) {
        int j = i - PACK_REL;
        int l = j >> 12, rem = j & 4095;
        int k = rem & 63, n = rem >> 6;
        WtFc[j] = f2bf(Wfc[(size_t)l * 4096 + k * 64 + n]);
    } else if (i < PACK_REL + PACK_FC + PACK_DIM) {
        int j = i - PACK_REL - PACK_FC;
        int k = j & 63, n = j >> 6;
        WtDim[j] = f2bf(Wdim[(size_t)k * 256 + n]);
    }
}

__global__ void cvt_bf16_kernel(const float* __restrict__ in, unsigned short* __restrict__ out,
                                int n) {
    int i = blockIdx.x * 256 + threadIdx.x;
    if (i < n) out[i] = f2bf(in[i]);
}

// --------------------------- MFMA GEMM (K=64) --------------------------------
// Single-relation projection: out row = [fs(256) | fd(256)] bf16. Grid (gx, 8).

__global__ __launch_bounds__(256) void gemm_proj(const unsigned short* __restrict__ hB,
                                                 const unsigned short* __restrict__ Wt,
                                                 unsigned short* __restrict__ out,
                                                 int M) {
    int tid = threadIdx.x;
    int wave = tid >> 6, lane = tid & 63;
    int q = lane >> 4, li = lane & 15;
    int nodeBase = blockIdx.x * 64 + (wave >> 1) * 32;
    int featBase = blockIdx.y * 64 + (wave & 1) * 32;

    const unsigned short* aptr[2];
    const unsigned short* bptr[2];
    #pragma unroll
    for (int t = 0; t < 2; ++t) {
        aptr[t] = Wt + (size_t)(featBase + t * 16 + li) * 64 + q * 8;
        int node = nodeBase + t * 16 + li; if (node >= M) node = M - 1;
        bptr[t] = hB + (size_t)node * 64 + q * 8;
    }
    f32x4 acc[2][2];
    #pragma unroll
    for (int a = 0; a < 2; ++a)
        #pragma unroll
        for (int bq = 0; bq < 2; ++bq)
            #pragma unroll
            for (int i = 0; i < 4; ++i) acc[a][bq][i] = 0.f;

    #pragma unroll
    for (int s = 0; s < 2; ++s) {
        bf16x8 a[2], b[2];
        #pragma unroll
        for (int t = 0; t < 2; ++t) {
            a[t] = *(const bf16x8*)(aptr[t] + s * 32);
            b[t] = *(const bf16x8*)(bptr[t] + s * 32);
        }
        #pragma unroll
        for (int ft = 0; ft < 2; ++ft)
            #pragma unroll
            for (int nt = 0; nt < 2; ++nt)
                acc[ft][nt] = __builtin_amdgcn_mfma_f32_16x16x32_bf16(a[ft], b[nt], acc[ft][nt], 0, 0, 0);
    }
    #pragma unroll
    for (int ft = 0; ft < 2; ++ft) {
        int f0 = featBase + ft * 16 + q * 4;
        #pragma unroll
        for (int nt = 0; nt < 2; ++nt) {
            int node = nodeBase + nt * 16 + li;
            if (node >= M) continue;
            unsigned lo = (unsigned)f2bf(acc[ft][nt][0]) | ((unsigned)f2bf(acc[ft][nt][1]) << 16);
            unsigned hi = (unsigned)f2bf(acc[ft][nt][2]) | ((unsigned)f2bf(acc[ft][nt][3]) << 16);
            uint2 pk; pk.x = lo; pk.y = hi;
            *(uint2*)(out + (size_t)node * 512 + f0) = pk;
        }
    }
}

__global__ __launch_bounds__(256) void gemm_f32out(const unsigned short* __restrict__ hB,
                                                   const unsigned short* __restrict__ Wt,
                                                   const float* __restrict__ bias,
                                                   float* __restrict__ out,
                                                   int M, int Nout, int relu) {
    int tid = threadIdx.x;
    int wave = tid >> 6, lane = tid & 63;
    int q = lane >> 4, li = lane & 15;
    int nodeBase = blockIdx.x * 64 + (wave >> 1) * 32;
    int featBase = blockIdx.y * 64 + (wave & 1) * 32;

    const unsigned short* aptr[2];
    const unsigned short* bptr[2];
    #pragma unroll
    for (int t = 0; t < 2; ++t) {
        aptr[t] = Wt + (size_t)(featBase + t * 16 + li) * 64 + q * 8;
        int node = nodeBase + t * 16 + li; if (node >= M) node = M - 1;
        bptr[t] = hB + (size_t)node * 64 + q * 8;
    }
    f32x4 acc[2][2];
    #pragma unroll
    for (int a = 0; a < 2; ++a)
        #pragma unroll
        for (int bq = 0; bq < 2; ++bq)
            #pragma unroll
            for (int i = 0; i < 4; ++i) acc[a][bq][i] = 0.f;

    #pragma unroll
    for (int s = 0; s < 2; ++s) {
        bf16x8 a[2], b[2];
        #pragma unroll
        for (int t = 0; t < 2; ++t) {
            a[t] = *(const bf16x8*)(aptr[t] + s * 32);
            b[t] = *(const bf16x8*)(bptr[t] + s * 32);
        }
        #pragma unroll
        for (int ft = 0; ft < 2; ++ft)
            #pragma unroll
            for (int nt = 0; nt < 2; ++nt)
                acc[ft][nt] = __builtin_amdgcn_mfma_f32_16x16x32_bf16(a[ft], b[nt], acc[ft][nt], 0, 0, 0);
    }
    #pragma unroll
    for (int ft = 0; ft < 2; ++ft) {
        int f0 = featBase + ft * 16 + q * 4;
        float b0 = bias[f0], b1 = bias[f0 + 1], b2 = bias[f0 + 2], b3 = bias[f0 + 3];
        #pragma unroll
        for (int nt = 0; nt < 2; ++nt) {
            int node = nodeBase + nt * 16 + li;
            if (node >= M) continue;
            float4 o;
            o.x = acc[ft][nt][0] + b0; o.y = acc[ft][nt][1] + b1;
            o.z = acc[ft][nt][2] + b2; o.w = acc[ft][nt][3] + b3;
            if (relu) {
                o.x = fmaxf(o.x, 0.f); o.y = fmaxf(o.y, 0.f);
                o.z = fmaxf(o.z, 0.f); o.w = fmaxf(o.w, 0.f);
            }
            *(float4*)(out + (size_t)node * Nout + f0) = o;
        }
    }
}

// ----------------- per-relation attention + accumulate -----------------------
// One wave per dst node, ONE relation per launch (proj buffer is L3-resident:
// 51.2 MB, just written by gemm_proj). Softmax without max-shift; fd pre-scaled
// by SCALE*log2e. rmode: 0 = first (overwrite hmf), 1 = accumulate,
// 2 = accumulate + emit bf16 hm (head-mean, /4).

__global__ __launch_bounds__(256) void agg_rel(const int* __restrict__ ro,
                                               const int* __restrict__ cs,
                                               const unsigned short* __restrict__ proj,
                                               float* __restrict__ hmf,
                                               unsigned short* __restrict__ hm,
                                               int rmode) {
    int wave = (blockIdx.x * 256 + threadIdx.x) >> 6;
    int lane = threadIdx.x & 63;
    if (wave >= N_NODES) return;
    int dst = wave;
    int base = ro[dst];
    int deg = ro[dst + 1] - base;

    float t0 = 0.f, t1 = 0.f, t2 = 0.f, t3 = 0.f;
    if (deg > 0) {
        uint2 fdr = *(const uint2*)(proj + (size_t)dst * 512 + 256 + lane * 4);
        const float FS = ATT_SCALE * LOG2E;
        float fd0 = bf2f(fdr.x & 0xffff) * FS;
        float fd1 = __uint_as_float(fdr.x & 0xffff0000u) * FS;
        float fd2 = bf2f(fdr.y & 0xffff) * FS;
        float fd3 = __uint_as_float(fdr.y & 0xffff0000u) * FS;

        float den = 0.f;
        const int* cse = cs + base;
        for (int c0 = 0; c0 < deg; c0 += 64) {
            int nc = deg - c0; if (nc > 64) nc = 64;
            int srcv = (lane < nc) ? cse[c0 + lane] : 0;
            for (int j0 = 0; j0 < nc; j0 += 8) {
                int nt = nc - j0; if (nt > 8) nt = 8;
                uint2 rowv[8];
                #pragma unroll
                for (int t = 0; t < 8; ++t) {
                    if (t < nt) {       // wave-uniform
                        int idx = __shfl(srcv, j0 + t, 64);
                        rowv[t] = *(const uint2*)(proj + (size_t)idx * 512 + lane * 4);
                    }
                }
                #pragma unroll
                for (int t = 0; t < 8; ++t) {
                    if (t < nt) {       // wave-uniform
                        float s0 = __uint_as_float(rowv[t].x << 16);
                        float s1 = __uint_as_float(rowv[t].x & 0xffff0000u);
                        float s2 = __uint_as_float(rowv[t].y << 16);
                        float s3 = __uint_as_float(rowv[t].y & 0xffff0000u);
                        float p = s0 * fd0 + s1 * fd1 + s2 * fd2 + s3 * fd3;
                        p = rowsum16(p);
                        p = fminf(fmaxf(p, -60.f), 60.f);
                        float pe = __builtin_amdgcn_exp2f(p);
                        den += pe;
                        t0 += pe * s0; t1 += pe * s1;
                        t2 += pe * s2; t3 += pe * s3;
                    }
                }
            }
        }
        float inv = 1.0f / fmaxf(den, 1e-9f);
        t0 *= inv; t1 *= inv; t2 *= inv; t3 *= inv;
    }

    // head-sum: feature f of head h lives at lane h*16 + f/4, slot f&3
    t0 += __shfl_xor(t0, 16, 64); t0 += __shfl_xor(t0, 32, 64);
    t1 += __shfl_xor(t1, 16, 64); t1 += __shfl_xor(t1, 32, 64);
    t2 += __shfl_xor(t2, 16, 64); t2 += __shfl_xor(t2, 32, 64);
    t3 += __shfl_xor(t3, 16, 64); t3 += __shfl_xor(t3, 32, 64);
    if (lane < 16) {
        float* ap = hmf + (size_t)dst * 64 + lane * 4;
        if (rmode > 0) {
            float4 old = *(float4*)ap;
            t0 += old.x; t1 += old.y; t2 += old.z; t3 += old.w;
        }
        if (rmode == 2) {
            unsigned lo = (unsigned)f2bf(t0 * 0.25f) | ((unsigned)f2bf(t1 * 0.25f) << 16);
            unsigned hi = (unsigned)f2bf(t2 * 0.25f) | ((unsigned)f2bf(t3 * 0.25f) << 16);
            uint2 pk; pk.x = lo; pk.y = hi;
            *(uint2*)(hm + (size_t)dst * 64 + lane * 4) = pk;
        } else {
            *(float4*)ap = make_float4(t0, t1, t2, t3);
        }
    }
}

// ----------------------------- batchnorm -------------------------------------

__global__ __launch_bounds__(256) void bn_reduce_kernel(const float* __restrict__ y,
                                                        float* __restrict__ acc1,
                                                        float* __restrict__ acc2) {
    int tid = threadIdx.x;
    int c = tid & 63;
    int g = tid >> 6;
    int rowStart = blockIdx.x * 4 + g;
    int stride = gridDim.x * 4;
    float s1 = 0.f, s2 = 0.f;
    for (int r = rowStart; r < N_NODES; r += stride) {
        float v = y[(size_t)r * 64 + c];
        s1 += v; s2 += v * v;
    }
    __shared__ float l1[4][64], l2[4][64];
    l1[g][c] = s1; l2[g][c] = s2;
    __syncthreads();
    if (g == 0) {
        s1 = l1[0][c] + l1[1][c] + l1[2][c] + l1[3][c];
        s2 = l2[0][c] + l2[1][c] + l2[2][c] + l2[3][c];
        atomicAdd(&acc1[c], s1);
        atomicAdd(&acc2[c], s2);
    }
}

__global__ void bn_apply_kernel(const float* __restrict__ y, const float* __restrict__ acc1,
                                const float* __restrict__ acc2, const float* __restrict__ gamma,
                                const float* __restrict__ beta,
                                unsigned short* __restrict__ outb) {
    int i = blockIdx.x * blockDim.x + threadIdx.x;
    if (i >= N_NODES * HID) return;
    int c = i & 63;
    const float invN = 1.0f / (float)N_NODES;
    float mu = acc1[c] * invN;
    float var = acc2[c] * invN - mu * mu;
    float v = gamma[c] * (y[i] - mu) * rsqrtf(var + EPS_BN) + beta[c];
    outb[i] = f2bf(v);
}

// ----------------------------- launch ----------------------------------------

extern "C" void kernel_launch(void* const* d_in, const int* in_sizes, int n_in,
                              void* d_out, int out_size, void* d_ws, size_t ws_size,
                              hipStream_t stream) {
    const float* x     = (const float*)d_in[0];
    const int* srcs[3] = {(const int*)d_in[1], (const int*)d_in[3], (const int*)d_in[5]};
    const int* dsts[3] = {(const int*)d_in[2], (const int*)d_in[4], (const int*)d_in[6]};
    const float* Wsrc  = (const float*)d_in[7];
    const float* Wdst  = (const float*)d_in[8];
    const float* Wfc   = (const float*)d_in[9];
    const float* bfc   = (const float*)d_in[10];
    const float* gamma = (const float*)d_in[11];
    const float* beta  = (const float*)d_in[12];
    const float* Wdim  = (const float*)d_in[13];
    const float* bdim  = (const float*)d_in[14];
    float* out = (float*)d_out;

    char* ws = (char*)d_ws;
    size_t off = 0;
    auto alloc = [&](size_t bytes) -> void* {
        void* p = ws + off;
        off += (bytes + 255) & ~(size_t)255;
        return p;
    };
    int* count    = (int*)alloc((size_t)3 * N_NODES * 4);
    int* cursor   = (int*)alloc((size_t)3 * N_NODES * 4);
    int* row_off  = (int*)alloc((size_t)3 * (N_NODES + 1) * 4);
    int* csr_src  = (int*)alloc((size_t)3 * E_EDGES * 4);
    int* bsum     = (int*)alloc(256 * 4);
    int* bpre     = (int*)alloc(256 * 4);
    unsigned short* proj  = (unsigned short*)alloc((size_t)N_NODES * 512 * 2);  // single, L3-tiled
    float* hmf            = (float*)alloc((size_t)N_NODES * HID * 4);
    unsigned short* hm    = (unsigned short*)alloc((size_t)N_NODES * HID * 2);
    float* ybuf           = (float*)alloc((size_t)N_NODES * HID * 4);
    unsigned short* xb    = (unsigned short*)alloc((size_t)N_NODES * HID * 2);
    unsigned short* hb0   = (unsigned short*)alloc((size_t)N_NODES * HID * 2);
    unsigned short* hb1   = (unsigned short*)alloc((size_t)N_NODES * HID * 2);
    unsigned short* WtRel = (unsigned short*)alloc((size_t)PACK_REL * 2);
    unsigned short* WtFc  = (unsigned short*)alloc((size_t)PACK_FC * 2);
    unsigned short* WtDim = (unsigned short*)alloc((size_t)PACK_DIM * 2);
    float* bnacc          = (float*)alloc(128 * 4);

    // CSR build
    hipMemsetAsync(count, 0, (size_t)3 * N_NODES * 4, stream);
    hist_kernel<<<(3 * E_EDGES + 255) / 256, 256, 0, stream>>>(dsts[0], dsts[1], dsts[2], count);
    scan_partial<<<3 * NCHUNK, 256, 0, stream>>>(count, bsum);
    scan_mid<<<1, 256, 0, stream>>>(bsum, bpre);
    scan_final<<<3 * NCHUNK, 256, 0, stream>>>(count, bpre, row_off, cursor);
    scatter_kernel<<<(3 * E_EDGES + 255) / 256, 256, 0, stream>>>(
        srcs[0], dsts[0], srcs[1], dsts[1], srcs[2], dsts[2], cursor, csr_src);

    // weight packing + input cast
    const int packTot = PACK_REL + PACK_FC + PACK_DIM;
    pack_all<<<(packTot + 255) / 256, 256, 0, stream>>>(Wsrc, Wdst, Wfc, Wdim,
                                                        WtRel, WtFc, WtDim);
    cvt_bf16_kernel<<<(N_NODES * HID + 255) / 256, 256, 0, stream>>>(x, xb, N_NODES * HID);

    const unsigned short* hcur = xb;
    unsigned short* hbufs[2] = {hb0, hb1};
    const int gx = (N_NODES + 63) / 64;   // 782
    for (int l = 0; l < L_LAYERS; ++l) {
        for (int r = 0; r < 3; ++r) {
            dim3 g(gx, 8);
            gemm_proj<<<g, 256, 0, stream>>>(hcur, WtRel + (size_t)(l * 3 + r) * 512 * 64,
                                             proj, N_NODES);
            agg_rel<<<(N_NODES + 3) / 4, 256, 0, stream>>>(
                row_off + (size_t)r * (N_NODES + 1), csr_src + (size_t)r * E_EDGES,
                proj, hmf, hm, r);
        }
        dim3 g2(gx, 1);
        gemm_f32out<<<g2, 256, 0, stream>>>(hm, WtFc + (size_t)l * 64 * 64, bfc + (size_t)l * HID,
                                            ybuf, N_NODES, 64, 1);
        hipMemsetAsync(bnacc, 0, 128 * 4, stream);
        bn_reduce_kernel<<<256, 256, 0, stream>>>(ybuf, bnacc, bnacc + 64);
        bn_apply_kernel<<<(N_NODES * HID + 255) / 256, 256, 0, stream>>>(
            ybuf, bnacc, bnacc + 64, gamma + (size_t)l * HID, beta + (size_t)l * HID, hbufs[l]);
        hcur = hbufs[l];
    }
    dim3 g3(gx, IN_DIM_ / 64);
    gemm_f32out<<<g3, 256, 0, stream>>>(hcur, WtDim, bdim, out, N_NODES, IN_DIM_, 0);
}

// Round 6
// 604.232 us; speedup vs baseline: 1.1058x; 1.1058x over previous
//
#include <hip/hip_runtime.h>
#include <math.h>

#define N_NODES 50000
#define E_EDGES 250000
#define HID 64
#define HD 256          // NHEADS * HID
#define L_LAYERS 2
#define IN_DIM_ 256
#define ATT_SCALE 0.125f
#define LOG2E 1.44269504f
#define EPS_BN 1e-5f
#define NCHUNK 49       // ceil(50000/1024)
#define GX 782          // ceil(50000/64)

#define PACK_REL (6 * 512 * 64)
#define PACK_FC  (2 * 64 * 64)
#define PACK_DIM (256 * 64)
#define HIST_B   2930   // ceil(750000/256)
#define PACK_B   864    // (PACK_REL+PACK_FC+PACK_DIM)/256
#define CVT_B    3125   // 3.2M/4/256
#define PROJ_B   (GX * 8 * 3)

typedef __attribute__((ext_vector_type(8))) short bf16x8;
typedef __attribute__((ext_vector_type(4))) float f32x4;

static __device__ __forceinline__ unsigned short f2bf(float f) {
    unsigned u = __float_as_uint(f);
    unsigned r = (u + 0x7fff + ((u >> 16) & 1)) >> 16;
    return (unsigned short)r;
}
static __device__ __forceinline__ float bf2f(unsigned u) {
    return __uint_as_float(u << 16);
}

// sum across each 16-lane row via DPP butterfly (4 VALU adds, no LDS)
static __device__ __forceinline__ float rowsum16(float x) {
    int t;
    t = __builtin_amdgcn_update_dpp(0, __float_as_int(x), 0xB1, 0xf, 0xf, true);  // quad_perm(1,0,3,2)
    x += __int_as_float(t);
    t = __builtin_amdgcn_update_dpp(0, __float_as_int(x), 0x4E, 0xf, 0xf, true);  // quad_perm(2,3,0,1)
    x += __int_as_float(t);
    t = __builtin_amdgcn_update_dpp(0, __float_as_int(x), 0x141, 0xf, 0xf, true); // row_half_mirror
    x += __int_as_float(t);
    t = __builtin_amdgcn_update_dpp(0, __float_as_int(x), 0x140, 0xf, 0xf, true); // row_mirror
    x += __int_as_float(t);
    return x;
}

// ----------------------------- scan (3-phase) --------------------------------

__global__ __launch_bounds__(256) void scan_partial(const int* __restrict__ count,
                                                    int* __restrict__ bsum) {
    int b = blockIdx.x;                 // 0..146
    int r = b / NCHUNK, ch = b - r * NCHUNK;
    int tid = threadIdx.x;
    int i0 = ch * 1024 + tid * 4;
    int s = 0;
    if (i0 + 3 < N_NODES) {
        int4 v = *(const int4*)(count + r * N_NODES + i0);
        s = v.x + v.y + v.z + v.w;
    } else {
        for (int j = 0; j < 4; ++j)
            if (i0 + j < N_NODES) s += count[r * N_NODES + i0 + j];
    }
    for (int o = 1; o < 64; o <<= 1) s += __shfl_xor(s, o, 64);
    __shared__ int wsum[4];
    if ((tid & 63) == 0) wsum[tid >> 6] = s;
    __syncthreads();
    if (tid == 0) bsum[b] = wsum[0] + wsum[1] + wsum[2] + wsum[3];
}

__global__ __launch_bounds__(256) void scan_mid(const int* __restrict__ bsum,
                                                int* __restrict__ bpre) {
    __shared__ int A[256], B[256];
    int tid = threadIdx.x;
    int v = (tid < 3 * NCHUNK) ? bsum[tid] : 0;
    int segStart = (tid / NCHUNK) * NCHUNK;
    A[tid] = v;
    __syncthreads();
    int* s = A; int* d = B;
    for (int o = 1; o < 256; o <<= 1) {
        int x = s[tid];
        if (tid - o >= segStart) x += s[tid - o];
        d[tid] = x;
        __syncthreads();
        int* t = s; s = d; d = t;
    }
    if (tid < 3 * NCHUNK) bpre[tid] = s[tid] - v;
}

__global__ __launch_bounds__(256) void scan_final(const int* __restrict__ count,
                                                  const int* __restrict__ bpre,
                                                  int* __restrict__ row_off,
                                                  int* __restrict__ cursor) {
    int b = blockIdx.x;
    int r = b / NCHUNK, ch = b - r * NCHUNK;
    int tid = threadIdx.x;
    int i0 = ch * 1024 + tid * 4;
    int v[4] = {0, 0, 0, 0};
    if (i0 + 3 < N_NODES) {
        int4 t = *(const int4*)(count + r * N_NODES + i0);
        v[0] = t.x; v[1] = t.y; v[2] = t.z; v[3] = t.w;
    } else {
        for (int j = 0; j < 4; ++j)
            if (i0 + j < N_NODES) v[j] = count[r * N_NODES + i0 + j];
    }
    int tsum = v[0] + v[1] + v[2] + v[3];
    __shared__ int A[256], B[256];
    A[tid] = tsum;
    __syncthreads();
    int* s = A; int* d = B;
    for (int o = 1; o < 256; o <<= 1) {
        int x = s[tid];
        if (tid >= o) x += s[tid - o];
        d[tid] = x;
        __syncthreads();
        int* t = s; s = d; d = t;
    }
    int run = bpre[b] + s[tid] - tsum;
    int* ro = row_off + r * (N_NODES + 1);
    int* cu = cursor + r * N_NODES;
    for (int j = 0; j < 4; ++j) {
        int idx = i0 + j;
        if (idx < N_NODES) { ro[idx] = run; cu[idx] = run; run += v[j]; }
    }
    if (ch == NCHUNK - 1 && tid == 255) ro[N_NODES] = E_EDGES;
}

// ----------------------- U1: hist ∪ pack ∪ cvt -------------------------------

__global__ __launch_bounds__(256) void u1_kernel(
        const int* __restrict__ d0, const int* __restrict__ d1, const int* __restrict__ d2,
        int* __restrict__ count,
        const float* __restrict__ Wsrc, const float* __restrict__ Wdst,
        const float* __restrict__ Wfc, const float* __restrict__ Wdim,
        unsigned short* __restrict__ WtRel, unsigned short* __restrict__ WtFc,
        unsigned short* __restrict__ WtDim,
        const float* __restrict__ x, unsigned short* __restrict__ xb) {
    int b = blockIdx.x;
    if (b < HIST_B) {
        int i = b * 256 + threadIdx.x;
        if (i < 3 * E_EDGES) {
            int r = i / E_EDGES;
            int e = i - r * E_EDGES;
            const int* dst = (r == 0) ? d0 : ((r == 1) ? d1 : d2);
            atomicAdd(&count[r * N_NODES + dst[e]], 1);
        }
    } else if (b < HIST_B + PACK_B) {
        int i = (b - HIST_B) * 256 + threadIdx.x;
        if (i < PACK_REL) {
            int k = i & 63;
            int n = (i >> 6) & 511;
            int lr = i >> 15;
            const float* srcm = (n < 256) ? Wsrc : Wdst;
            WtRel[i] = f2bf(srcm[((size_t)lr * 64 + k) * 256 + (n & 255)]);
        } else if (i < PACK_REL + PACK_FC) {
            int j = i - PACK_REL;
            int l = j >> 12, rem = j & 4095;
            int k = rem & 63, n = rem >> 6;
            WtFc[j] = f2bf(Wfc[(size_t)l * 4096 + k * 64 + n]);
        } else if (i < PACK_REL + PACK_FC + PACK_DIM) {
            int j = i - PACK_REL - PACK_FC;
            int k = j & 63, n = j >> 6;
            WtDim[j] = f2bf(Wdim[(size_t)k * 256 + n]);
        }
    } else {
        int i = ((b - HIST_B - PACK_B) * 256 + threadIdx.x) * 4;
        if (i < N_NODES * HID) {
            float4 v = *(const float4*)(x + i);
            uint2 o;
            o.x = (unsigned)f2bf(v.x) | ((unsigned)f2bf(v.y) << 16);
            o.y = (unsigned)f2bf(v.z) | ((unsigned)f2bf(v.w) << 16);
            *(uint2*)(xb + i) = o;
        }
    }
}

// --------------------------- MFMA projection body ----------------------------
// D'[feat][node]: A-frag from Wt[512][64], B-frag from h[M][64]. C/D:
// col=lane&15 (node), row=quad*4+reg (feature) -> lane owns 4 consecutive
// features of one node: packed 8B bf16 store. No LDS, no barriers.

static __device__ __forceinline__ void proj_body(int bx, int by,
        const unsigned short* __restrict__ hB, const unsigned short* __restrict__ Wt,
        unsigned short* __restrict__ out, int M) {
    int tid = threadIdx.x;
    int wave = tid >> 6, lane = tid & 63;
    int q = lane >> 4, li = lane & 15;
    int nodeBase = bx * 64 + (wave >> 1) * 32;
    int featBase = by * 64 + (wave & 1) * 32;

    const unsigned short* aptr[2];
    const unsigned short* bptr[2];
    #pragma unroll
    for (int t = 0; t < 2; ++t) {
        aptr[t] = Wt + (size_t)(featBase + t * 16 + li) * 64 + q * 8;
        int node = nodeBase + t * 16 + li; if (node >= M) node = M - 1;
        bptr[t] = hB + (size_t)node * 64 + q * 8;
    }
    f32x4 acc[2][2];
    #pragma unroll
    for (int a = 0; a < 2; ++a)
        #pragma unroll
        for (int bq = 0; bq < 2; ++bq)
            #pragma unroll
            for (int i = 0; i < 4; ++i) acc[a][bq][i] = 0.f;

    #pragma unroll
    for (int s = 0; s < 2; ++s) {
        bf16x8 a[2], b[2];
        #pragma unroll
        for (int t = 0; t < 2; ++t) {
            a[t] = *(const bf16x8*)(aptr[t] + s * 32);
            b[t] = *(const bf16x8*)(bptr[t] + s * 32);
        }
        #pragma unroll
        for (int ft = 0; ft < 2; ++ft)
            #pragma unroll
            for (int nt = 0; nt < 2; ++nt)
                acc[ft][nt] = __builtin_amdgcn_mfma_f32_16x16x32_bf16(a[ft], b[nt], acc[ft][nt], 0, 0, 0);
    }
    #pragma unroll
    for (int ft = 0; ft < 2; ++ft) {
        int f0 = featBase + ft * 16 + q * 4;
        #pragma unroll
        for (int nt = 0; nt < 2; ++nt) {
            int node = nodeBase + nt * 16 + li;
            if (node >= M) continue;
            unsigned lo = (unsigned)f2bf(acc[ft][nt][0]) | ((unsigned)f2bf(acc[ft][nt][1]) << 16);
            unsigned hi = (unsigned)f2bf(acc[ft][nt][2]) | ((unsigned)f2bf(acc[ft][nt][3]) << 16);
            uint2 pk; pk.x = lo; pk.y = hi;
            *(uint2*)(out + (size_t)node * 512 + f0) = pk;
        }
    }
}

// ------------------- U2: scatter ∪ proj(layer 0, 3 rel) ----------------------

__global__ __launch_bounds__(256) void u2_kernel(
        const int* __restrict__ s0, const int* __restrict__ d0,
        const int* __restrict__ s1, const int* __restrict__ d1,
        const int* __restrict__ s2, const int* __restrict__ d2,
        int* __restrict__ cursor, int* __restrict__ csr_src,
        const unsigned short* __restrict__ xb, const unsigned short* __restrict__ WtRel0,
        unsigned short* __restrict__ p0, unsigned short* __restrict__ p1,
        unsigned short* __restrict__ p2) {
    int b = blockIdx.x;
    if (b < HIST_B) {
        int i = b * 256 + threadIdx.x;
        if (i < 3 * E_EDGES) {
            int r = i / E_EDGES;
            int e = i - r * E_EDGES;
            const int* src = (r == 0) ? s0 : ((r == 1) ? s1 : s2);
            const int* dst = (r == 0) ? d0 : ((r == 1) ? d1 : d2);
            int dd = dst[e];
            int pos = atomicAdd(&cursor[r * N_NODES + dd], 1);
            csr_src[r * E_EDGES + pos] = src[e];
        }
    } else {
        int b2 = b - HIST_B;
        int px = b2 % GX;
        int rem = b2 / GX;
        int py = rem & 7;
        int pz = rem >> 3;
        unsigned short* out = (pz == 0) ? p0 : ((pz == 1) ? p1 : p2);
        proj_body(px, py, xb, WtRel0 + (size_t)pz * 512 * 64, out, N_NODES);
    }
}

// proj for layer 1 (no CSR work to overlap)
__global__ __launch_bounds__(256) void gemm_proj3(const unsigned short* __restrict__ hB,
                                                  const unsigned short* __restrict__ WtL,
                                                  unsigned short* __restrict__ p0,
                                                  unsigned short* __restrict__ p1,
                                                  unsigned short* __restrict__ p2,
                                                  int M) {
    int r = blockIdx.z;
    unsigned short* out = (r == 0) ? p0 : ((r == 1) ? p1 : p2);
    proj_body(blockIdx.x, blockIdx.y, hB, WtL + (size_t)r * 512 * 64, out, M);
}

__global__ __launch_bounds__(256) void gemm_f32out(const unsigned short* __restrict__ hB,
                                                   const unsigned short* __restrict__ Wt,
                                                   const float* __restrict__ bias,
                                                   float* __restrict__ out,
                                                   int M, int Nout, int relu) {
    int tid = threadIdx.x;
    int wave = tid >> 6, lane = tid & 63;
    int q = lane >> 4, li = lane & 15;
    int nodeBase = blockIdx.x * 64 + (wave >> 1) * 32;
    int featBase = blockIdx.y * 64 + (wave & 1) * 32;

    const unsigned short* aptr[2];
    const unsigned short* bptr[2];
    #pragma unroll
    for (int t = 0; t < 2; ++t) {
        aptr[t] = Wt + (size_t)(featBase + t * 16 + li) * 64 + q * 8;
        int node = nodeBase + t * 16 + li; if (node >= M) node = M - 1;
        bptr[t] = hB + (size_t)node * 64 + q * 8;
    }
    f32x4 acc[2][2];
    #pragma unroll
    for (int a = 0; a < 2; ++a)
        #pragma unroll
        for (int bq = 0; bq < 2; ++bq)
            #pragma unroll
            for (int i = 0; i < 4; ++i) acc[a][bq][i] = 0.f;

    #pragma unroll
    for (int s = 0; s < 2; ++s) {
        bf16x8 a[2], b[2];
        #pragma unroll
        for (int t = 0; t < 2; ++t) {
            a[t] = *(const bf16x8*)(aptr[t] + s * 32);
            b[t] = *(const bf16x8*)(bptr[t] + s * 32);
        }
        #pragma unroll
        for (int ft = 0; ft < 2; ++ft)
            #pragma unroll
            for (int nt = 0; nt < 2; ++nt)
                acc[ft][nt] = __builtin_amdgcn_mfma_f32_16x16x32_bf16(a[ft], b[nt], acc[ft][nt], 0, 0, 0);
    }
    #pragma unroll
    for (int ft = 0; ft < 2; ++ft) {
        int f0 = featBase + ft * 16 + q * 4;
        float b0 = bias[f0], b1 = bias[f0 + 1], b2 = bias[f0 + 2], b3 = bias[f0 + 3];
        #pragma unroll
        for (int nt = 0; nt < 2; ++nt) {
            int node = nodeBase + nt * 16 + li;
            if (node >= M) continue;
            float4 o;
            o.x = acc[ft][nt][0] + b0; o.y = acc[ft][nt][1] + b1;
            o.z = acc[ft][nt][2] + b2; o.w = acc[ft][nt][3] + b3;
            if (relu) {
                o.x = fmaxf(o.x, 0.f); o.y = fmaxf(o.y, 0.f);
                o.z = fmaxf(o.z, 0.f); o.w = fmaxf(o.w, 0.f);
            }
            *(float4*)(out + (size_t)node * Nout + f0) = o;
        }
    }
}

// ----------------- fused attention: 3 relations + head-mean ------------------
// One wave per dst node. proj row: [fs(256) | fd(256)] bf16. 16-deep gather
// batches for MLP. Softmax without max-shift (|logit| clamped); fd pre-scaled
// by SCALE*log2e. bf16 unpack via bit tricks; dot reduce via DPP butterfly.

__global__ __launch_bounds__(256) void agg_fused(const int* __restrict__ row_off,
                                                 const int* __restrict__ csr_src,
                                                 const unsigned short* __restrict__ p0,
                                                 const unsigned short* __restrict__ p1,
                                                 const unsigned short* __restrict__ p2,
                                                 unsigned short* __restrict__ hm) {
    int wave = (blockIdx.x * 256 + threadIdx.x) >> 6;
    int lane = threadIdx.x & 63;
    if (wave >= N_NODES) return;
    int dst = wave;

    float t0 = 0.f, t1 = 0.f, t2 = 0.f, t3 = 0.f;

    #pragma unroll
    for (int r = 0; r < 3; ++r) {
        const unsigned short* proj = (r == 0) ? p0 : ((r == 1) ? p1 : p2);
        const int* ro = row_off + r * (N_NODES + 1);
        int base = ro[dst];
        int deg = ro[dst + 1] - base;
        if (deg == 0) continue;

        uint2 fdr = *(const uint2*)(proj + (size_t)dst * 512 + 256 + lane * 4);
        const float FS = ATT_SCALE * LOG2E;
        float fd0 = bf2f(fdr.x & 0xffff) * FS;
        float fd1 = __uint_as_float(fdr.x & 0xffff0000u) * FS;
        float fd2 = bf2f(fdr.y & 0xffff) * FS;
        float fd3 = __uint_as_float(fdr.y & 0xffff0000u) * FS;

        float den = 0.f;
        float a0 = 0.f, a1 = 0.f, a2 = 0.f, a3 = 0.f;
        const int* cs = csr_src + (size_t)r * E_EDGES + base;

        for (int c0 = 0; c0 < deg; c0 += 64) {
            int nc = deg - c0; if (nc > 64) nc = 64;
            int srcv = (lane < nc) ? cs[c0 + lane] : 0;
            for (int j0 = 0; j0 < nc; j0 += 16) {
                int nt = nc - j0; if (nt > 16) nt = 16;
                uint2 rowv[16];
                #pragma unroll
                for (int t = 0; t < 16; ++t) {
                    if (t < nt) {       // wave-uniform
                        int idx = __shfl(srcv, j0 + t, 64);
                        rowv[t] = *(const uint2*)(proj + (size_t)idx * 512 + lane * 4);
                    }
                }
                #pragma unroll
                for (int t = 0; t < 16; ++t) {
                    if (t < nt) {       // wave-uniform
                        float s0 = __uint_as_float(rowv[t].x << 16);
                        float s1 = __uint_as_float(rowv[t].x & 0xffff0000u);
                        float s2 = __uint_as_float(rowv[t].y << 16);
                        float s3 = __uint_as_float(rowv[t].y & 0xffff0000u);
                        float p = s0 * fd0 + s1 * fd1 + s2 * fd2 + s3 * fd3;
                        p = rowsum16(p);
                        p = fminf(fmaxf(p, -60.f), 60.f);
                        float pe = __builtin_amdgcn_exp2f(p);
                        den += pe;
                        a0 += pe * s0; a1 += pe * s1;
                        a2 += pe * s2; a3 += pe * s3;
                    }
                }
            }
        }
        float inv = 1.0f / fmaxf(den, 1e-9f);
        t0 += a0 * inv; t1 += a1 * inv; t2 += a2 * inv; t3 += a3 * inv;
    }

    // mean over heads: feature f of head h lives at lane h*16 + f/4, slot f&3
    t0 += __shfl_xor(t0, 16, 64); t0 += __shfl_xor(t0, 32, 64);
    t1 += __shfl_xor(t1, 16, 64); t1 += __shfl_xor(t1, 32, 64);
    t2 += __shfl_xor(t2, 16, 64); t2 += __shfl_xor(t2, 32, 64);
    t3 += __shfl_xor(t3, 16, 64); t3 += __shfl_xor(t3, 32, 64);
    if (lane < 16) {
        unsigned lo = (unsigned)f2bf(t0 * 0.25f) | ((unsigned)f2bf(t1 * 0.25f) << 16);
        unsigned hi = (unsigned)f2bf(t2 * 0.25f) | ((unsigned)f2bf(t3 * 0.25f) << 16);
        uint2 pk; pk.x = lo; pk.y = hi;
        *(uint2*)(hm + (size_t)dst * 64 + lane * 4) = pk;
    }
}

// ----------------------------- batchnorm -------------------------------------

__global__ __launch_bounds__(256) void bn_reduce_kernel(const float* __restrict__ y,
                                                        float* __restrict__ acc1,
                                                        float* __restrict__ acc2) {
    int tid = threadIdx.x;
    int c = tid & 63;
    int g = tid >> 6;
    int rowStart = blockIdx.x * 4 + g;
    int stride = gridDim.x * 4;
    float s1 = 0.f, s2 = 0.f;
    for (int r = rowStart; r < N_NODES; r += stride) {
        float v = y[(size_t)r * 64 + c];
        s1 += v; s2 += v * v;
    }
    __shared__ float l1[4][64], l2[4][64];
    l1[g][c] = s1; l2[g][c] = s2;
    __syncthreads();
    if (g == 0) {
        s1 = l1[0][c] + l1[1][c] + l1[2][c] + l1[3][c];
        s2 = l2[0][c] + l2[1][c] + l2[2][c] + l2[3][c];
        atomicAdd(&acc1[c], s1);
        atomicAdd(&acc2[c], s2);
    }
}

__global__ void bn_apply_kernel(const float* __restrict__ y, const float* __restrict__ acc1,
                                const float* __restrict__ acc2, const float* __restrict__ gamma,
                                const float* __restrict__ beta,
                                unsigned short* __restrict__ outb) {
    int i = blockIdx.x * blockDim.x + threadIdx.x;
    if (i >= N_NODES * HID) return;
    int c = i & 63;
    const float invN = 1.0f / (float)N_NODES;
    float mu = acc1[c] * invN;
    float var = acc2[c] * invN - mu * mu;
    float v = gamma[c] * (y[i] - mu) * rsqrtf(var + EPS_BN) + beta[c];
    outb[i] = f2bf(v);
}

// ----------------------------- launch ----------------------------------------

extern "C" void kernel_launch(void* const* d_in, const int* in_sizes, int n_in,
                              void* d_out, int out_size, void* d_ws, size_t ws_size,
                              hipStream_t stream) {
    const float* x     = (const float*)d_in[0];
    const int* srcs[3] = {(const int*)d_in[1], (const int*)d_in[3], (const int*)d_in[5]};
    const int* dsts[3] = {(const int*)d_in[2], (const int*)d_in[4], (const int*)d_in[6]};
    const float* Wsrc  = (const float*)d_in[7];
    const float* Wdst  = (const float*)d_in[8];
    const float* Wfc   = (const float*)d_in[9];
    const float* bfc   = (const float*)d_in[10];
    const float* gamma = (const float*)d_in[11];
    const float* beta  = (const float*)d_in[12];
    const float* Wdim  = (const float*)d_in[13];
    const float* bdim  = (const float*)d_in[14];
    float* out = (float*)d_out;

    char* ws = (char*)d_ws;
    size_t off = 0;
    auto alloc = [&](size_t bytes) -> void* {
        void* p = ws + off;
        off += (bytes + 255) & ~(size_t)255;
        return p;
    };
    // bnacc + count contiguous so one memset zeros both
    float* bnacc  = (float*)alloc(256 * 4);                    // [0..127] l0, [128..255] l1
    int* count    = (int*)alloc((size_t)3 * N_NODES * 4);
    int* cursor   = (int*)alloc((size_t)3 * N_NODES * 4);
    int* row_off  = (int*)alloc((size_t)3 * (N_NODES + 1) * 4);
    int* csr_src  = (int*)alloc((size_t)3 * E_EDGES * 4);
    int* bsum     = (int*)alloc(256 * 4);
    int* bpre     = (int*)alloc(256 * 4);
    unsigned short* proj0 = (unsigned short*)alloc((size_t)N_NODES * 512 * 2);
    unsigned short* proj1 = (unsigned short*)alloc((size_t)N_NODES * 512 * 2);
    unsigned short* proj2 = (unsigned short*)alloc((size_t)N_NODES * 512 * 2);
    unsigned short* hm    = (unsigned short*)alloc((size_t)N_NODES * HID * 2);
    float* ybuf           = (float*)alloc((size_t)N_NODES * HID * 4);
    unsigned short* xb    = (unsigned short*)alloc((size_t)N_NODES * HID * 2);
    unsigned short* hb0   = (unsigned short*)alloc((size_t)N_NODES * HID * 2);
    unsigned short* hb1   = (unsigned short*)alloc((size_t)N_NODES * HID * 2);
    unsigned short* WtRel = (unsigned short*)alloc((size_t)PACK_REL * 2);
    unsigned short* WtFc  = (unsigned short*)alloc((size_t)PACK_FC * 2);
    unsigned short* WtDim = (unsigned short*)alloc((size_t)PACK_DIM * 2);

    // one memset covers bnacc (1 KB) + count (600 KB), contiguous
    hipMemsetAsync(bnacc, 0, 1024 + (size_t)3 * N_NODES * 4, stream);

    // U1: hist ∪ weight-pack ∪ x->bf16 cast
    u1_kernel<<<HIST_B + PACK_B + CVT_B, 256, 0, stream>>>(
        dsts[0], dsts[1], dsts[2], count, Wsrc, Wdst, Wfc, Wdim,
        WtRel, WtFc, WtDim, x, xb);

    scan_partial<<<3 * NCHUNK, 256, 0, stream>>>(count, bsum);
    scan_mid<<<1, 256, 0, stream>>>(bsum, bpre);
    scan_final<<<3 * NCHUNK, 256, 0, stream>>>(count, bpre, row_off, cursor);

    // U2: scatter ∪ proj(layer 0)
    u2_kernel<<<HIST_B + PROJ_B, 256, 0, stream>>>(
        srcs[0], dsts[0], srcs[1], dsts[1], srcs[2], dsts[2],
        cursor, csr_src, xb, WtRel, proj0, proj1, proj2);

    unsigned short* hbufs[2] = {hb0, hb1};
    const unsigned short* hcur = xb;
    for (int l = 0; l < L_LAYERS; ++l) {
        if (l > 0) {
            dim3 g(GX, 8, 3);
            gemm_proj3<<<g, 256, 0, stream>>>(hcur, WtRel + (size_t)l * 3 * 512 * 64,
                                              proj0, proj1, proj2, N_NODES);
        }
        agg_fused<<<(N_NODES + 3) / 4, 256, 0, stream>>>(row_off, csr_src,
                                                         proj0, proj1, proj2, hm);
        dim3 g2(GX, 1);
        gemm_f32out<<<g2, 256, 0, stream>>>(hm, WtFc + (size_t)l * 64 * 64, bfc + (size_t)l * HID,
                                            ybuf, N_NODES, 64, 1);
        float* ba = bnacc + l * 128;
        bn_reduce_kernel<<<256, 256, 0, stream>>>(ybuf, ba, ba + 64);
        bn_apply_kernel<<<(N_NODES * HID + 255) / 256, 256, 0, stream>>>(
            ybuf, ba, ba + 64, gamma + (size_t)l * HID, beta + (size_t)l * HID, hbufs[l]);
        hcur = hbufs[l];
    }
    dim3 g3(GX, IN_DIM_ / 64);
    gemm_f32out<<<g3, 256, 0, stream>>>(hcur, WtDim, bdim, out, N_NODES, IN_DIM_, 0);
}